// Round 10
// baseline (607.567 us; speedup 1.0000x reference)
//
#include <hip/hip_runtime.h>

// Problem constants (fixed by the reference setup_inputs).
#define VSZ 50000   // vocab
#define ESZ 100     // embedding dim
#define HSZ 64      // hidden
#define GSZ 256     // 4*H (gate width, PyTorch order i,f,g,o)
#define BSZ 256     // batch
#define TSZ 512     // seq len

typedef _Float16 halfv2 __attribute__((ext_vector_type(2)));
typedef _Float16 half8  __attribute__((ext_vector_type(8)));

__device__ __forceinline__ float fast_rcp(float x) { return __builtin_amdgcn_rcpf(x); }
__device__ __forceinline__ float sigmoid_f(float x) { return fast_rcp(1.f + __expf(-x)); }
__device__ __forceinline__ float tanh_f(float x) {
    float e = __expf(2.f * x);
    return 1.f - 2.f * fast_rcp(e + 1.f);
}
__device__ __forceinline__ float fdot2f(halfv2 a, halfv2 b, float c) {
    return __builtin_amdgcn_fdot2(a, b, c, false);   // f16*f16 -> f32 acc
}
__device__ __forceinline__ halfv2 h2at(half8 v, int m) {   // constant m only
    halfv2 r; r[0] = v[2 * m]; r[1] = v[2 * m + 1]; return r;
}

// ---------------------------------------------------------------------------
// Kernel A: G[v, col] = sum_e emb[v,e]*w_ih0[row,e] + b_ih0[row] + b_hh0[row],
// PERMUTED col = 4*(row%64) + row/64. r5 s_load form (measured fastest: r4
// vector-broadcast 255us, r7 LDS-broadcast 134us, this ~107us). Unchanged.
// ---------------------------------------------------------------------------
__global__ __launch_bounds__(256) void build_table(
    const float* __restrict__ emb, const float* __restrict__ w_ih0,
    const float* __restrict__ b_ih0, const float* __restrict__ b_hh0,
    float* __restrict__ Gt)
{
    const int g = threadIdx.x;            // PyTorch gate-row index 0..255
    const int row0 = blockIdx.x * 32;
    const int col = ((g & 63) << 2) + (g >> 6);   // permuted column

    float w[ESZ];
    #pragma unroll
    for (int e = 0; e < ESZ; e += 4) {
        float4 v = *(const float4*)(w_ih0 + g * ESZ + e);
        w[e] = v.x; w[e + 1] = v.y; w[e + 2] = v.z; w[e + 3] = v.w;
    }
    const float bias = b_ih0[g] + b_hh0[g];

    #pragma unroll 1
    for (int r = row0; r < row0 + 32 && r < VSZ; r += 4) {
        const int off0 = __builtin_amdgcn_readfirstlane(r * ESZ);
        const float* e0 = emb + off0;
        const float* e1 = e0 + ESZ;
        const float* e2 = e0 + 2 * ESZ;
        const float* e3 = e0 + 3 * ESZ;
        float a0 = bias, a1 = 0.f, a2 = 0.f, a3 = 0.f;
        float b0 = bias, b1 = 0.f, b2 = 0.f, b3 = 0.f;
        float c0 = bias, c1 = 0.f, c2 = 0.f, c3 = 0.f;
        float d0 = bias, d1 = 0.f, d2 = 0.f, d3 = 0.f;
        #pragma unroll
        for (int e = 0; e < ESZ; e += 4) {
            a0 += e0[e    ] * w[e    ]; a1 += e0[e + 1] * w[e + 1];
            a2 += e0[e + 2] * w[e + 2]; a3 += e0[e + 3] * w[e + 3];
            b0 += e1[e    ] * w[e    ]; b1 += e1[e + 1] * w[e + 1];
            b2 += e1[e + 2] * w[e + 2]; b3 += e1[e + 3] * w[e + 3];
            c0 += e2[e    ] * w[e    ]; c1 += e2[e + 1] * w[e + 1];
            c2 += e2[e + 2] * w[e + 2]; c3 += e2[e + 3] * w[e + 3];
            d0 += e3[e    ] * w[e    ]; d1 += e3[e + 1] * w[e + 1];
            d2 += e3[e + 2] * w[e + 2]; d3 += e3[e + 3] * w[e + 3];
        }
        Gt[(size_t)r       * GSZ + col] = (a0 + a1) + (a2 + a3);
        Gt[(size_t)(r + 1) * GSZ + col] = (b0 + b1) + (b2 + b3);
        Gt[(size_t)(r + 2) * GSZ + col] = (c0 + c1) + (c2 + c3);
        Gt[(size_t)(r + 3) * GSZ + col] = (d0 + d1) + (d2 + d3);
    }
}

// ---------------------------------------------------------------------------
// Kernel B: fused 2-layer LSTM + FC head, 1 block (1024 thr) per batch row.
//
// r10 redesign (r9 needed ~59 regs vs the allocator's de-facto ~52 budget ->
// permanent spill + per-step remat). New decomposition fits UNDER the budget:
// wave w owns units 4w..4w+3 ENTIRELY. lane = (ql, gt, j):
//   q = 4w+ql (hidden unit), gt = gate type (i,f,g,o), j = K-slice.
// Per thread: ONE gate-row (grow = gt*64+q) x 16-K slice of each of
// {w_hh0, w_ih1, w_hh1} = 24 halfv2 regs total. Per step, each thread:
//   L0 dot (8 fdot2, vs h0[16j..+16))  [step k]
//   L1 dot (16 fdot2, vs h0 and h1 slices)  [step k-1, software-pipelined]
//   j-fold allreduce (2 DPP shfl each)
//   j==0: + xg / bias -> ONE act per layer
//   gate-gather: shfl_xor 4/8/12 (swizzles, valid at gt==0 j==0)
//   c,h update + publish at 1 lane/unit; h double-buffered in LDS
// ONE lgkm-only barrier per step (Gt prefetch stays in flight across it).
// Everything intra-wave except the h publish/read.
// ---------------------------------------------------------------------------
__device__ __forceinline__ void sync_lds() {
    asm volatile("s_waitcnt lgkmcnt(0)\n\ts_barrier" ::: "memory");
}
#define PINH(v) asm volatile("" : "+v"(v))

__global__ void lstm_fused(
    const int* __restrict__ x, const float* __restrict__ Gt,
    const float* __restrict__ w_hh0,
    const float* __restrict__ w_ih1, const float* __restrict__ w_hh1,
    const float* __restrict__ b_ih1, const float* __restrict__ b_hh1,
    const float* __restrict__ fc_w, const float* __restrict__ fc_b,
    float* __restrict__ out)
{
    const int tid  = threadIdx.x;          // 0..1023
    const int b    = blockIdx.x;
    const int lane = tid & 63;
    const int wv   = tid >> 6;             // wave 0..15
    const int q    = wv * 4 + (lane >> 4); // hidden unit 0..63
    const int gt   = (lane >> 2) & 3;      // gate type
    const int j    = lane & 3;             // K-slice
    const int grow = gt * HSZ + q;         // PyTorch gate-row

    __shared__ __align__(16) _Float16 h0b[2][HSZ];
    __shared__ __align__(16) _Float16 h1b[2][HSZ];
    __shared__ int xtok[TSZ];

    // Weight slices: 16 fp32 -> 8 halfv2 each.
    halfv2 w0[8], wi[8], wh[8];
    {
        const float* p0 = w_hh0 + grow * HSZ + 16 * j;
        const float* pi = w_ih1 + grow * HSZ + 16 * j;
        const float* ph = w_hh1 + grow * HSZ + 16 * j;
        #pragma unroll
        for (int m = 0; m < 4; ++m) {
            float4 f = *(const float4*)(p0 + 4 * m);
            w0[2*m]   = halfv2{(_Float16)f.x, (_Float16)f.y};
            w0[2*m+1] = halfv2{(_Float16)f.z, (_Float16)f.w};
            f = *(const float4*)(pi + 4 * m);
            wi[2*m]   = halfv2{(_Float16)f.x, (_Float16)f.y};
            wi[2*m+1] = halfv2{(_Float16)f.z, (_Float16)f.w};
            f = *(const float4*)(ph + 4 * m);
            wh[2*m]   = halfv2{(_Float16)f.x, (_Float16)f.y};
            wh[2*m+1] = halfv2{(_Float16)f.z, (_Float16)f.w};
        }
    }
    #pragma unroll
    for (int m = 0; m < 8; ++m) { PINH(w0[m]); PINH(wi[m]); PINH(wh[m]); }

    const float bias1 = b_ih1[grow] + b_hh1[grow];
    const float mco = (gt == 2) ?  2.f : -1.f;   // unified activation consts
    const float Aco = (gt == 2) ?  1.f :  0.f;
    const float Bco = (gt == 2) ? -2.f :  1.f;

    if (tid < 128)      ((_Float16*)h0b)[tid] = (_Float16)0.f;
    else if (tid < 256) ((_Float16*)h1b)[tid - 128] = (_Float16)0.f;
    if (tid < TSZ) xtok[tid] = x[b * TSZ + tid];
    __syncthreads();

    float c0 = 0.f, c1 = 0.f;
    float xg_cur = 0.f;
    if (j == 0) xg_cur = Gt[(size_t)xtok[0] * GSZ + 4 * q + gt];

    #pragma unroll 1
    for (int k = 0; k <= TSZ; ++k) {
        // Prefetch next token's gate scalar (survives the lgkm barrier).
        float xg_nxt = 0.f;
        if (j == 0 && k + 1 < TSZ)
            xg_nxt = Gt[(size_t)xtok[k + 1] * GSZ + 4 * q + gt];

        // h slices (fp16; 4 distinct 32B slices per wave -> broadcast reads).
        const _Float16* h0p = h0b[(k ^ 1) & 1];   // h0(k-1)
        const _Float16* h1p = h1b[k & 1];         // h1(k-2)
        half8 ha0 = *(const half8*)(h0p + 16 * j);
        half8 ha1 = *(const half8*)(h0p + 16 * j + 8);
        float d = 0.f, e = 0.f;
        #pragma unroll
        for (int m = 0; m < 4; ++m) {
            halfv2 h = h2at(ha0, m);
            d = fdot2f(w0[m], h, d); e = fdot2f(wi[m], h, e);
        }
        #pragma unroll
        for (int m = 0; m < 4; ++m) {
            halfv2 h = h2at(ha1, m);
            d = fdot2f(w0[4+m], h, d); e = fdot2f(wi[4+m], h, e);
        }
        half8 hb0 = *(const half8*)(h1p + 16 * j);
        half8 hb1 = *(const half8*)(h1p + 16 * j + 8);
        #pragma unroll
        for (int m = 0; m < 4; ++m) {
            e = fdot2f(wh[m],   h2at(hb0, m), e);
            e = fdot2f(wh[4+m], h2at(hb1, m), e);
        }

        // j-fold allreduce (quad = lanes differing in bits 0..1).
        d += __shfl_xor(d, 1, 64); d += __shfl_xor(d, 2, 64);
        e += __shfl_xor(e, 1, 64); e += __shfl_xor(e, 2, 64);

        // One activation per layer, at j==0 lanes only.
        float aL0 = 0.f, aL1 = 0.f;
        if (j == 0) {
            float s0 = d + xg_cur;
            aL0 = fmaf(Bco, fast_rcp(1.f + __expf(mco * s0)), Aco);
            float s1 = e + bias1;
            aL1 = fmaf(Bco, fast_rcp(1.f + __expf(mco * s1)), Aco);
        }

        // Gate gather: valid at gt==0, j==0 lanes (i = own act).
        float f0 = __shfl_xor(aL0, 4, 64);     // gate 1 (f)
        float g0 = __shfl_xor(aL0, 8, 64);     // gate 2 (g)
        float o0 = __shfl_xor(aL0, 12, 64);    // gate 3 (o)
        float f1 = __shfl_xor(aL1, 4, 64);
        float g1 = __shfl_xor(aL1, 8, 64);
        float o1 = __shfl_xor(aL1, 12, 64);

        if ((lane & 15) == 0) {                // gt==0 && j==0: unit owner
            if (k < TSZ) {                     // layer-0 step k
                c0 = f0 * c0 + aL0 * g0;
                float hn = o0 * tanh_f(c0);
                h0b[k & 1][q] = (_Float16)hn;
            }
            if (k >= 1) {                      // layer-1 step k-1
                c1 = f1 * c1 + aL1 * g1;
                float hn = o1 * tanh_f(c1);
                h1b[(k ^ 1) & 1][q] = (_Float16)hn;
            }
        }
        xg_cur = xg_nxt;
        sync_lds();                            // lgkm-only; vmem in flight
    }

    // FC head on h1(T-1) = h1b[1] (wave 0 only; TSZ even -> parity 1).
    if (tid < HSZ) {
        float v = fmaxf((float)h1b[1][tid], 0.f) * fc_w[tid];
        #pragma unroll
        for (int off = 32; off > 0; off >>= 1) v += __shfl_down(v, off, 64);
        if (tid == 0) out[b] = sigmoid_f(v + fc_b[0]);
    }
}

extern "C" void kernel_launch(void* const* d_in, const int* in_sizes, int n_in,
                              void* d_out, int out_size, void* d_ws, size_t ws_size,
                              hipStream_t stream) {
    const int*   x     = (const int*)  d_in[0];
    const float* emb   = (const float*)d_in[1];
    const float* w_ih0 = (const float*)d_in[2];
    const float* w_hh0 = (const float*)d_in[3];
    const float* b_ih0 = (const float*)d_in[4];
    const float* b_hh0 = (const float*)d_in[5];
    const float* w_ih1 = (const float*)d_in[6];
    const float* w_hh1 = (const float*)d_in[7];
    const float* b_ih1 = (const float*)d_in[8];
    const float* b_hh1 = (const float*)d_in[9];
    const float* fc_w  = (const float*)d_in[10];
    const float* fc_b  = (const float*)d_in[11];
    float* out = (float*)d_out;

    // Workspace: permuted G table [V, 4H] fp32 = 51.2 MB.
    float* Gt = (float*)d_ws;

    build_table<<<dim3((VSZ + 31) / 32), dim3(256), 0, stream>>>(
        emb, w_ih0, b_ih0, b_hh0, Gt);
    lstm_fused<<<dim3(BSZ), dim3(1024), 0, stream>>>(
        x, Gt, w_hh0, w_ih1, w_hh1, b_ih1, b_hh1, fc_w, fc_b, out);
}